// Round 8
// baseline (343.471 us; speedup 1.0000x reference)
//
#include <hip/hip_runtime.h>
#include <hip/hip_fp16.h>

// out = h@Wd1 + (softmax(h@M@e^T)@e)@W2,  M=Wq@Wk^T (folded on device).
// Round-8: phase-stagger via 2 co-resident blocks/CU at the proven no-spill
// register level. 512 thr (8 waves), NB=16 (32 rows), split algebra
// (G1: T=H@M, acc[2][4]; G2: out=[H|U]@Wdt K=1024, acc[2][4]), two 32KB
// panels = 64KB LDS, launch_bounds(512,4) -> 2 blocks/CU, 4 waves/SIMD,
// VGPR budget 128 (no spill). Global-direct B with 1-deep prefetch.

#define B_TOT   16384
#define TQn     2
#define TKn     5
#define NB      16
#define THREADS 512

typedef _Float16 f16;
typedef _Float16 f16x8 __attribute__((ext_vector_type(8)));
typedef _Float16 f16x4 __attribute__((ext_vector_type(4)));
typedef _Float16 f16x2 __attribute__((ext_vector_type(2)));
typedef float    f32x4 __attribute__((ext_vector_type(4)));

#define HPAN 0
#define TPAN 32768
#define LDS_TOTAL 65536

#define MFMA16(a,b,c) __builtin_amdgcn_mfma_f32_16x16x32_f16(a, b, c, 0, 0, 0)

__global__ __launch_bounds__(THREADS, 4) void fused_attn(
    const float* __restrict__ hptr, const float* __restrict__ eptr,
    const f16* __restrict__ Mt, const f16* __restrict__ Wdt,
    float* __restrict__ outp)
{
  extern __shared__ char smem[];
  const int tid  = threadIdx.x;
  const int lane = tid & 63;
  const int w    = tid >> 6;             // wave 0..7
  const int g    = lane >> 4;
  const int l15  = lane & 15;
  const int b0   = blockIdx.x * NB;
  const int n0   = w * 64;               // wave's output-col base (4 n-frags)
  const int xsw  = (l15 & 7) << 4;

  // ---- stage H: fp32 global -> f16 LDS (swizzled), 32 rows x 512 ----
  #pragma unroll
  for (int i = 0; i < 8; ++i) {
    int c   = tid + THREADS * i;         // 4096 float4 = 32 rows x 128
    int row = c >> 7;
    int k4  = c & 127;
    int tq  = row & 1;
    int b   = b0 + (row >> 1);
    float4 v = *reinterpret_cast<const float4*>(
        hptr + ((size_t)(tq * B_TOT + b) << 9) + (k4 << 2));
    f16x4 p;
    p[0] = (f16)v.x; p[1] = (f16)v.y; p[2] = (f16)v.z; p[3] = (f16)v.w;
    *reinterpret_cast<f16x4*>(smem + HPAN + row * 1024 +
                              ((k4 << 3) ^ ((row & 7) << 4))) = p;
  }
  __syncthreads();   // H staged

  // ---- GEMM1: T[32x512] = H @ Mt (wave owns 64 cols), acc[2][4] ----
  {
    f32x4 acc[2][4];
    #pragma unroll
    for (int fm = 0; fm < 2; ++fm)
      #pragma unroll
      for (int fn = 0; fn < 4; ++fn)
        acc[fm][fn] = (f32x4){0.f, 0.f, 0.f, 0.f};
    f16x8 bc[4], bn[4];
    #pragma unroll
    for (int fn = 0; fn < 4; ++fn)
      bc[fn] = *reinterpret_cast<const f16x8*>(
          Mt + (size_t)(n0 + (fn << 4) + l15) * 512 + (g << 3));
    for (int kt = 0; kt < 16; ++kt) {
      f16x8 af0 = *reinterpret_cast<const f16x8*>(
          smem + HPAN + l15 * 1024 + (((kt << 6) + (g << 4)) ^ xsw));
      f16x8 af1 = *reinterpret_cast<const f16x8*>(
          smem + HPAN + (16 + l15) * 1024 + (((kt << 6) + (g << 4)) ^ xsw));
      if (kt < 15) {
        #pragma unroll
        for (int fn = 0; fn < 4; ++fn)
          bn[fn] = *reinterpret_cast<const f16x8*>(
              Mt + (size_t)(n0 + (fn << 4) + l15) * 512 + (kt + 1) * 32 + (g << 3));
      }
      __builtin_amdgcn_s_setprio(1);
      #pragma unroll
      for (int fn = 0; fn < 4; ++fn) {
        acc[0][fn] = MFMA16(af0, bc[fn], acc[0][fn]);
        acc[1][fn] = MFMA16(af1, bc[fn], acc[1][fn]);
      }
      __builtin_amdgcn_s_setprio(0);
      if (kt < 15) {
        #pragma unroll
        for (int fn = 0; fn < 4; ++fn) bc[fn] = bn[fn];
      }
    }
    // T -> TPAN (C/D map: row=(lane>>4)*4+reg, col=lane&15)
    #pragma unroll
    for (int fm = 0; fm < 2; ++fm)
      #pragma unroll
      for (int fn = 0; fn < 4; ++fn)
        #pragma unroll
        for (int r = 0; r < 4; ++r) {
          int row = (fm << 4) + (g << 2) + r;
          int col = n0 + (fn << 4) + l15;
          *reinterpret_cast<f16*>(smem + TPAN + row * 1024 +
                                  ((col << 1) ^ ((row & 7) << 4))) = (f16)acc[fm][fn][r];
        }
  }
  __syncthreads();   // all T visible

  // ---- softmax + u = att@e (2 batches per wave; rows 4w..4w+3 wave-private) ----
  #pragma unroll 1
  for (int bi = 0; bi < 2; ++bi) {
    const int bl = (w << 1) + bi;
    const int b  = b0 + bl;
    f16x8 evh[TKn];
    #pragma unroll 1
    for (int j = 0; j < TKn; ++j) {
      const float4* p4 = reinterpret_cast<const float4*>(
          eptr + ((size_t)(j * B_TOT + b) << 9) + (lane << 3));
      float4 u0 = p4[0], u1 = p4[1];
      evh[j][0] = (f16)u0.x; evh[j][1] = (f16)u0.y;
      evh[j][2] = (f16)u0.z; evh[j][3] = (f16)u0.w;
      evh[j][4] = (f16)u1.x; evh[j][5] = (f16)u1.y;
      evh[j][6] = (f16)u1.z; evh[j][7] = (f16)u1.w;
    }
    f16x8 tvh[TQn];
    #pragma unroll
    for (int i = 0; i < TQn; ++i) {
      int row = (bl << 1) + i;
      tvh[i] = *reinterpret_cast<const f16x8*>(
          smem + TPAN + row * 1024 + ((lane << 4) ^ ((row & 7) << 4)));
    }
    float s[TQn][TKn];
    #pragma unroll
    for (int i = 0; i < TQn; ++i)
      #pragma unroll
      for (int j = 0; j < TKn; ++j) {
        float a = 0.f;
        #pragma unroll
        for (int p = 0; p < 4; ++p) {
          f16x2 ta = {tvh[i][2 * p], tvh[i][2 * p + 1]};
          f16x2 ea = {evh[j][2 * p], evh[j][2 * p + 1]};
          a = __builtin_amdgcn_fdot2(ta, ea, a, false);
        }
        s[i][j] = a;
      }
    #pragma unroll
    for (int d = 1; d < 64; d <<= 1)
      #pragma unroll
      for (int i = 0; i < TQn; ++i)
        #pragma unroll
        for (int j = 0; j < TKn; ++j)
          s[i][j] += __shfl_xor(s[i][j], d, 64);
    #pragma unroll
    for (int i = 0; i < TQn; ++i) {
      float mx = s[i][0];
      #pragma unroll
      for (int j = 1; j < TKn; ++j) mx = fmaxf(mx, s[i][j]);
      float sum = 0.f;
      #pragma unroll
      for (int j = 0; j < TKn; ++j) { float e = __expf(s[i][j] - mx); s[i][j] = e; sum += e; }
      float rs = 1.0f / sum;
      int row = (bl << 1) + i;
      f16x8 uv;
      #pragma unroll
      for (int m = 0; m < 8; ++m) {
        float ua = 0.f;
        #pragma unroll
        for (int j = 0; j < TKn; ++j) ua += s[i][j] * (float)evh[j][m];
        uv[m] = (f16)(ua * rs);
      }
      *reinterpret_cast<f16x8*>(
          smem + TPAN + row * 1024 + ((lane << 4) ^ ((row & 7) << 4))) = uv;
    }
  }
  __syncthreads();   // all U visible (H panel untouched)

  // ---- GEMM2: OUT[32x512] = [H|U] @ Wdt (K=1024), acc[2][4] ----
  {
    f32x4 acc[2][4];
    #pragma unroll
    for (int fm = 0; fm < 2; ++fm)
      #pragma unroll
      for (int fn = 0; fn < 4; ++fn)
        acc[fm][fn] = (f32x4){0.f, 0.f, 0.f, 0.f};
    f16x8 bc[4], bn[4];
    #pragma unroll
    for (int fn = 0; fn < 4; ++fn)
      bc[fn] = *reinterpret_cast<const f16x8*>(
          Wdt + (size_t)(n0 + (fn << 4) + l15) * 1024 + (g << 3));
    for (int kt = 0; kt < 32; ++kt) {
      char* ab = smem + ((kt >> 4) << 15);   // HPAN kt<16, TPAN kt>=16
      f16x8 af0 = *reinterpret_cast<const f16x8*>(
          ab + l15 * 1024 + ((((kt & 15) << 6) + (g << 4)) ^ xsw));
      f16x8 af1 = *reinterpret_cast<const f16x8*>(
          ab + (16 + l15) * 1024 + ((((kt & 15) << 6) + (g << 4)) ^ xsw));
      if (kt < 31) {
        #pragma unroll
        for (int fn = 0; fn < 4; ++fn)
          bn[fn] = *reinterpret_cast<const f16x8*>(
              Wdt + (size_t)(n0 + (fn << 4) + l15) * 1024 + (kt + 1) * 32 + (g << 3));
      }
      __builtin_amdgcn_s_setprio(1);
      #pragma unroll
      for (int fn = 0; fn < 4; ++fn) {
        acc[0][fn] = MFMA16(af0, bc[fn], acc[0][fn]);
        acc[1][fn] = MFMA16(af1, bc[fn], acc[1][fn]);
      }
      __builtin_amdgcn_s_setprio(0);
      if (kt < 31) {
        #pragma unroll
        for (int fn = 0; fn < 4; ++fn) bc[fn] = bn[fn];
      }
    }
    // epilogue: fp32 store
    #pragma unroll
    for (int fm = 0; fm < 2; ++fm)
      #pragma unroll
      for (int fn = 0; fn < 4; ++fn)
        #pragma unroll
        for (int r = 0; r < 4; ++r) {
          int row = (fm << 4) + (g << 2) + r;
          int col = n0 + (fn << 4) + l15;
          int tq  = row & 1;
          int bb  = b0 + (row >> 1);
          outp[((size_t)(tq * B_TOT + bb) << 9) + col] = acc[fm][fn][r];
        }
  }
}

// ---- prep: Mt[n][k]=(WqWk^T)[k][n]; Wdt[n][k<512]=Wdown[k][n];
//      Wdt[n][512+k2]=(Wv@Wd2)[k2][n] ----
__global__ __launch_bounds__(256) void prep_all(
    const float* __restrict__ Wq, const float* __restrict__ Wk,
    const float* __restrict__ Wv, const float* __restrict__ Wdown,
    f16* __restrict__ Mt, f16* __restrict__ Wdt)
{
  __shared__ float sA[32][68];
  __shared__ float sB[32][68];
  const int tid = threadIdx.x;
  const int bx  = blockIdx.x;

  if (bx < 512) {
    const bool mt  = (bx < 256);
    const int  bb  = mt ? bx : bx - 256;
    const int  n0  = (bb & 15) << 5;
    const int  k0  = (bb >> 4) << 5;
    float accv[4] = {0.f, 0.f, 0.f, 0.f};
    for (int e0 = 0; e0 < 512; e0 += 64) {
      if (mt) {
        #pragma unroll
        for (int i = 0; i < 2; ++i) {
          int c = tid + (i << 8);
          int r = c >> 4, e4 = (c & 15) << 2;
          *reinterpret_cast<float4*>(&sA[r][e4]) =
              *reinterpret_cast<const float4*>(Wq + ((k0 + r) << 9) + e0 + e4);
          *reinterpret_cast<float4*>(&sB[r][e4]) =
              *reinterpret_cast<const float4*>(Wk + ((n0 + r) << 9) + e0 + e4);
        }
      } else {
        #pragma unroll
        for (int i = 0; i < 2; ++i) {
          int c = tid + (i << 8);
          int r = c >> 4, e4 = (c & 15) << 2;
          *reinterpret_cast<float4*>(&sA[r][e4]) =
              *reinterpret_cast<const float4*>(Wv + ((k0 + r) << 9) + e0 + e4);
        }
        #pragma unroll
        for (int i = 0; i < 8; ++i) {
          int c = tid + (i << 8);
          int el = c >> 5, nl = c & 31;
          sB[nl][el] = Wdown[((512 + e0 + el) << 9) + n0 + nl];
        }
      }
      __syncthreads();
      #pragma unroll
      for (int i = 0; i < 4; ++i) {
        int o = tid + (i << 8);
        int nl = o >> 5, kl = o & 31;
        float sacc = accv[i];
        #pragma unroll
        for (int e = 0; e < 64; e += 4) {
          float4 a  = *reinterpret_cast<const float4*>(&sA[kl][e]);
          float4 bq = *reinterpret_cast<const float4*>(&sB[nl][e]);
          sacc += a.x * bq.x + a.y * bq.y + a.z * bq.z + a.w * bq.w;
        }
        accv[i] = sacc;
      }
      __syncthreads();
    }
    #pragma unroll
    for (int i = 0; i < 4; ++i) {
      int o = tid + (i << 8);
      int nl = o >> 5, kl = o & 31;
      if (mt) Mt[((n0 + nl) << 9) + k0 + kl] = (f16)accv[i];
      else    Wdt[((n0 + nl) << 10) + 512 + k0 + kl] = (f16)accv[i];
    }
  } else {
    const int bb = bx - 512;
    const int n0 = (bb & 15) << 5;
    const int k0 = (bb >> 4) << 5;
    #pragma unroll
    for (int i = 0; i < 4; ++i) {
      int c = tid + (i << 8);
      int r = c >> 5, nl = c & 31;
      sA[r][nl] = Wdown[((k0 + r) << 9) + n0 + nl];
    }
    __syncthreads();
    #pragma unroll
    for (int i = 0; i < 4; ++i) {
      int c = tid + (i << 8);
      int nl = c >> 5, kl = c & 31;
      Wdt[((n0 + nl) << 10) + k0 + kl] = (f16)sA[kl][nl];
    }
  }
}

extern "C" void kernel_launch(void* const* d_in, const int* in_sizes, int n_in,
                              void* d_out, int out_size, void* d_ws, size_t ws_size,
                              hipStream_t stream) {
  const float* h   = (const float*)d_in[0];
  const float* enc = (const float*)d_in[1];
  const float* Wq  = (const float*)d_in[2];
  const float* Wk  = (const float*)d_in[3];
  const float* Wv  = (const float*)d_in[4];
  const float* Wd  = (const float*)d_in[5];
  float* out = (float*)d_out;

  f16* Mt  = (f16*)d_ws;            // 512x512 f16
  f16* Wdt = Mt + 512 * 512;        // 512x1024 f16

  (void)hipFuncSetAttribute(reinterpret_cast<const void*>(fused_attn),
                            hipFuncAttributeMaxDynamicSharedMemorySize, LDS_TOTAL);

  prep_all<<<768, 256, 0, stream>>>(Wq, Wk, Wv, Wd, Mt, Wdt);
  fused_attn<<<B_TOT / NB, THREADS, LDS_TOTAL, stream>>>(h, enc, Mt, Wdt, out);
}

// Round 9
// 206.364 us; speedup vs baseline: 1.6644x; 1.6644x over previous
//
#include <hip/hip_runtime.h>
#include <hip/hip_fp16.h>

// out = h@Wd1 + (softmax(h@M@e^T)@e)@W2,  M=Wq@Wk^T, W2=Wv@Wd2 (folded on device).
// Round-9: merged G1 [T|O1]=H@Mt2 (O1 in regs, H dies) -> ONE 64KB panel
// (H -> T -> U in place). Global-direct B (L2-hot weights), interleaved
// half-step prefetch, FREE-RUNNING GEMM loops (no per-step barriers; 4 block
// barriers total). NB=32, 1024 thr, (1024,4) = 128-reg budget (no spill).

#define B_TOT   16384
#define TQn     2
#define TKn     5
#define NB      32
#define THREADS 1024

typedef _Float16 f16;
typedef _Float16 f16x8 __attribute__((ext_vector_type(8)));
typedef _Float16 f16x4 __attribute__((ext_vector_type(4)));
typedef _Float16 f16x2 __attribute__((ext_vector_type(2)));
typedef float    f32x4 __attribute__((ext_vector_type(4)));

#define MFMA16(a,b,c) __builtin_amdgcn_mfma_f32_16x16x32_f16(a, b, c, 0, 0, 0)

__global__ __launch_bounds__(THREADS, 4) void fused_attn(
    const float* __restrict__ hptr, const float* __restrict__ eptr,
    const f16* __restrict__ Mt2, const f16* __restrict__ W2t,
    float* __restrict__ outp)
{
  __shared__ char smem[65536];           // 64 rows x 1024B panel (H -> T -> U)
  const int tid  = threadIdx.x;
  const int lane = tid & 63;
  const int w    = tid >> 6;             // wave 0..15
  const int g    = lane >> 4;
  const int l15  = lane & 15;
  const int b0   = blockIdx.x * NB;
  const int n0   = w * 32;               // wave's col base (each N-half)
  const int xsw  = (l15 & 7) << 4;

  // ---- stage H: fp32 global -> f16 LDS (swizzled), 64 rows x 512 ----
  #pragma unroll
  for (int i = 0; i < 8; ++i) {
    int c   = tid + THREADS * i;         // 8192 float4 = 64 rows x 128
    int row = c >> 7;
    int k4  = c & 127;
    int tq  = row & 1;
    int b   = b0 + (row >> 1);
    float4 v = *reinterpret_cast<const float4*>(
        hptr + ((size_t)(tq * B_TOT + b) << 9) + (k4 << 2));
    f16x4 p;
    p[0] = (f16)v.x; p[1] = (f16)v.y; p[2] = (f16)v.z; p[3] = (f16)v.w;
    *reinterpret_cast<f16x4*>(smem + row * 1024 + ((k4 << 3) ^ ((row & 7) << 4))) = p;
  }

  // B base pointers (per-lane rows of Mt2): T-half rows n0+l15(+16), O-half +512
  const f16* bT0 = Mt2 + (size_t)(n0 + l15) * 512 + (g << 3);
  const f16* bT1 = bT0 + 16 * 512;
  const f16* bO0 = bT0 + 512 * 512;
  const f16* bO1 = bO0 + 16 * 512;
  f16x8 bcT0 = *reinterpret_cast<const f16x8*>(bT0);
  f16x8 bcT1 = *reinterpret_cast<const f16x8*>(bT1);

  __syncthreads();   // H staged

  // ---- GEMM1 (free-running): [T|O1] = H @ Mt2, acc_t/acc_o [4][2] ----
  f32x4 acc_t[4][2], acc_o[4][2];
  #pragma unroll
  for (int fm = 0; fm < 4; ++fm)
    #pragma unroll
    for (int fn = 0; fn < 2; ++fn) {
      acc_t[fm][fn] = (f32x4){0.f, 0.f, 0.f, 0.f};
      acc_o[fm][fn] = (f32x4){0.f, 0.f, 0.f, 0.f};
    }

  for (int c = 0; c < 16; ++c) {
    f16x8 af[4];
    #pragma unroll
    for (int fm = 0; fm < 4; ++fm)
      af[fm] = *reinterpret_cast<const f16x8*>(
          smem + (fm * 16 + l15) * 1024 + (((c << 6) + (g << 4)) ^ xsw));
    // issue O-half loads for this step (covered by T-half MFMAs)
    f16x8 bcO0 = *reinterpret_cast<const f16x8*>(bO0 + c * 32);
    f16x8 bcO1 = *reinterpret_cast<const f16x8*>(bO1 + c * 32);
    __builtin_amdgcn_s_setprio(1);
    #pragma unroll
    for (int fm = 0; fm < 4; ++fm) {
      acc_t[fm][0] = MFMA16(af[fm], bcT0, acc_t[fm][0]);
      acc_t[fm][1] = MFMA16(af[fm], bcT1, acc_t[fm][1]);
    }
    __builtin_amdgcn_s_setprio(0);
    // issue T-half loads for next step (covered by O-half MFMAs)
    if (c < 15) {
      bcT0 = *reinterpret_cast<const f16x8*>(bT0 + (c + 1) * 32);
      bcT1 = *reinterpret_cast<const f16x8*>(bT1 + (c + 1) * 32);
    }
    __builtin_amdgcn_s_setprio(1);
    #pragma unroll
    for (int fm = 0; fm < 4; ++fm) {
      acc_o[fm][0] = MFMA16(af[fm], bcO0, acc_o[fm][0]);
      acc_o[fm][1] = MFMA16(af[fm], bcO1, acc_o[fm][1]);
    }
    __builtin_amdgcn_s_setprio(0);
  }
  __syncthreads();   // WAR: all waves done reading H before T overwrites panel

  // ---- T -> panel f16 (C/D map: row=(lane>>4)*4+reg, col=lane&15) ----
  #pragma unroll
  for (int fm = 0; fm < 4; ++fm)
    #pragma unroll
    for (int fn = 0; fn < 2; ++fn)
      #pragma unroll
      for (int r = 0; r < 4; ++r) {
        int row = (fm << 4) + (g << 2) + r;
        int col = n0 + (fn << 4) + l15;
        *reinterpret_cast<f16*>(smem + row * 1024 +
                                ((col << 1) ^ ((row & 7) << 4))) = (f16)acc_t[fm][fn][r];
      }
  __syncthreads();   // all T visible

  // ---- softmax + u = att@e (2 batches per wave), full-ILP enc loads ----
  #pragma unroll 1
  for (int bi = 0; bi < 2; ++bi) {
    const int bl = (w << 1) + bi;
    const int b  = b0 + bl;
    float4 e0[TKn], e1[TKn];
    #pragma unroll
    for (int j = 0; j < TKn; ++j) {
      const float4* p4 = reinterpret_cast<const float4*>(
          eptr + ((size_t)(j * B_TOT + b) << 9) + (lane << 3));
      e0[j] = p4[0];
      e1[j] = p4[1];
    }
    f16x8 evh[TKn];
    #pragma unroll
    for (int j = 0; j < TKn; ++j) {
      evh[j][0] = (f16)e0[j].x; evh[j][1] = (f16)e0[j].y;
      evh[j][2] = (f16)e0[j].z; evh[j][3] = (f16)e0[j].w;
      evh[j][4] = (f16)e1[j].x; evh[j][5] = (f16)e1[j].y;
      evh[j][6] = (f16)e1[j].z; evh[j][7] = (f16)e1[j].w;
    }
    f16x8 tvh[TQn];
    #pragma unroll
    for (int i = 0; i < TQn; ++i) {
      int row = (bl << 1) + i;
      tvh[i] = *reinterpret_cast<const f16x8*>(
          smem + row * 1024 + ((lane << 4) ^ ((row & 7) << 4)));
    }
    float s[TQn][TKn];
    #pragma unroll
    for (int i = 0; i < TQn; ++i)
      #pragma unroll
      for (int j = 0; j < TKn; ++j) {
        float a = 0.f;
        #pragma unroll
        for (int p = 0; p < 4; ++p) {
          f16x2 ta = {tvh[i][2 * p], tvh[i][2 * p + 1]};
          f16x2 ea = {evh[j][2 * p], evh[j][2 * p + 1]};
          a = __builtin_amdgcn_fdot2(ta, ea, a, false);
        }
        s[i][j] = a;
      }
    #pragma unroll
    for (int d = 1; d < 64; d <<= 1)
      #pragma unroll
      for (int i = 0; i < TQn; ++i)
        #pragma unroll
        for (int j = 0; j < TKn; ++j)
          s[i][j] += __shfl_xor(s[i][j], d, 64);
    #pragma unroll
    for (int i = 0; i < TQn; ++i) {
      float mx = s[i][0];
      #pragma unroll
      for (int j = 1; j < TKn; ++j) mx = fmaxf(mx, s[i][j]);
      float sum = 0.f;
      #pragma unroll
      for (int j = 0; j < TKn; ++j) { float e = __expf(s[i][j] - mx); s[i][j] = e; sum += e; }
      float rs = 1.0f / sum;
      int row = (bl << 1) + i;
      f16x8 uv;
      #pragma unroll
      for (int m = 0; m < 8; ++m) {
        float ua = 0.f;
        #pragma unroll
        for (int j = 0; j < TKn; ++j) ua += s[i][j] * (float)evh[j][m];
        uv[m] = (f16)(ua * rs);
      }
      *reinterpret_cast<f16x8*>(
          smem + row * 1024 + ((lane << 4) ^ ((row & 7) << 4))) = uv;
    }
  }
  __syncthreads();   // all U visible

  // ---- GEMM2 (free-running): acc_o += U @ W2t (K=512) ----
  {
    const f16* bW0 = W2t + (size_t)(n0 + l15) * 512 + (g << 3);
    const f16* bW1 = bW0 + 16 * 512;
    f16x8 bc0 = *reinterpret_cast<const f16x8*>(bW0);
    f16x8 bc1 = *reinterpret_cast<const f16x8*>(bW1);
    for (int kt = 0; kt < 16; ++kt) {
      f16x8 uf[4];
      #pragma unroll
      for (int fm = 0; fm < 4; ++fm)
        uf[fm] = *reinterpret_cast<const f16x8*>(
            smem + (fm * 16 + l15) * 1024 + (((kt << 6) + (g << 4)) ^ xsw));
      f16x8 bn0, bn1;
      if (kt < 15) {
        bn0 = *reinterpret_cast<const f16x8*>(bW0 + (kt + 1) * 32);
        bn1 = *reinterpret_cast<const f16x8*>(bW1 + (kt + 1) * 32);
      }
      __builtin_amdgcn_s_setprio(1);
      #pragma unroll
      for (int fm = 0; fm < 4; ++fm) {
        acc_o[fm][0] = MFMA16(uf[fm], bc0, acc_o[fm][0]);
        acc_o[fm][1] = MFMA16(uf[fm], bc1, acc_o[fm][1]);
      }
      __builtin_amdgcn_s_setprio(0);
      if (kt < 15) { bc0 = bn0; bc1 = bn1; }
    }
  }

  // ---- epilogue: fp32 store ----
  #pragma unroll
  for (int fm = 0; fm < 4; ++fm)
    #pragma unroll
    for (int fn = 0; fn < 2; ++fn)
      #pragma unroll
      for (int r = 0; r < 4; ++r) {
        int row = (fm << 4) + (g << 2) + r;
        int col = n0 + (fn << 4) + l15;
        int tq  = row & 1;
        int bb  = b0 + (row >> 1);
        outp[((size_t)(tq * B_TOT + bb) << 9) + col] = acc_o[fm][fn][r];
      }
}

// ---- prep: Mt2[n][k] (n<512: (WqWk^T)^T; n>=512: Wdown[k][n-512]), W2t[n][k]=(Wv@Wd2)^T ----
__global__ __launch_bounds__(256) void prep_all(
    const float* __restrict__ Wq, const float* __restrict__ Wk,
    const float* __restrict__ Wv, const float* __restrict__ Wdown,
    f16* __restrict__ Mt2, f16* __restrict__ W2t)
{
  __shared__ float sA[32][68];
  __shared__ float sB[32][68];
  const int tid = threadIdx.x;
  const int bx  = blockIdx.x;

  if (bx < 512) {
    const bool mt  = (bx < 256);
    const int  bb  = mt ? bx : bx - 256;
    const int  n0  = (bb & 15) << 5;
    const int  k0  = (bb >> 4) << 5;
    float accv[4] = {0.f, 0.f, 0.f, 0.f};
    for (int e0 = 0; e0 < 512; e0 += 64) {
      if (mt) {
        #pragma unroll
        for (int i = 0; i < 2; ++i) {
          int c = tid + (i << 8);
          int r = c >> 4, e4 = (c & 15) << 2;
          *reinterpret_cast<float4*>(&sA[r][e4]) =
              *reinterpret_cast<const float4*>(Wq + ((k0 + r) << 9) + e0 + e4);
          *reinterpret_cast<float4*>(&sB[r][e4]) =
              *reinterpret_cast<const float4*>(Wk + ((n0 + r) << 9) + e0 + e4);
        }
      } else {
        #pragma unroll
        for (int i = 0; i < 2; ++i) {
          int c = tid + (i << 8);
          int r = c >> 4, e4 = (c & 15) << 2;
          *reinterpret_cast<float4*>(&sA[r][e4]) =
              *reinterpret_cast<const float4*>(Wv + ((k0 + r) << 9) + e0 + e4);
        }
        #pragma unroll
        for (int i = 0; i < 8; ++i) {
          int c = tid + (i << 8);
          int el = c >> 5, nl = c & 31;
          sB[nl][el] = Wdown[((512 + e0 + el) << 9) + n0 + nl];
        }
      }
      __syncthreads();
      #pragma unroll
      for (int i = 0; i < 4; ++i) {
        int o = tid + (i << 8);
        int nl = o >> 5, kl = o & 31;
        float sacc = accv[i];
        #pragma unroll
        for (int e = 0; e < 64; e += 4) {
          float4 a  = *reinterpret_cast<const float4*>(&sA[kl][e]);
          float4 bq = *reinterpret_cast<const float4*>(&sB[nl][e]);
          sacc += a.x * bq.x + a.y * bq.y + a.z * bq.z + a.w * bq.w;
        }
        accv[i] = sacc;
      }
      __syncthreads();
    }
    #pragma unroll
    for (int i = 0; i < 4; ++i) {
      int o = tid + (i << 8);
      int nl = o >> 5, kl = o & 31;
      if (mt) Mt2[((n0 + nl) << 9) + k0 + kl] = (f16)accv[i];
      else    W2t[((n0 + nl) << 9) + k0 + kl] = (f16)accv[i];
    }
  } else {
    const int bb = bx - 512;
    const int n0 = (bb & 15) << 5;
    const int k0 = (bb >> 4) << 5;
    #pragma unroll
    for (int i = 0; i < 4; ++i) {
      int c = tid + (i << 8);
      int r = c >> 5, nl = c & 31;
      sA[r][nl] = Wdown[((k0 + r) << 9) + n0 + nl];
    }
    __syncthreads();
    #pragma unroll
    for (int i = 0; i < 4; ++i) {
      int c = tid + (i << 8);
      int nl = c >> 5, kl = c & 31;
      Mt2[((512 + n0 + nl) << 9) + k0 + kl] = (f16)sA[kl][nl];
    }
  }
}

extern "C" void kernel_launch(void* const* d_in, const int* in_sizes, int n_in,
                              void* d_out, int out_size, void* d_ws, size_t ws_size,
                              hipStream_t stream) {
  const float* h   = (const float*)d_in[0];
  const float* enc = (const float*)d_in[1];
  const float* Wq  = (const float*)d_in[2];
  const float* Wk  = (const float*)d_in[3];
  const float* Wv  = (const float*)d_in[4];
  const float* Wd  = (const float*)d_in[5];
  float* out = (float*)d_out;

  f16* Mt2 = (f16*)d_ws;              // 1024 x 512 f16 = 1MB
  f16* W2t = Mt2 + 1024 * 512;        // 512 x 512 f16 = 0.5MB

  prep_all<<<768, 256, 0, stream>>>(Wq, Wk, Wv, Wd, Mt2, W2t);
  fused_attn<<<B_TOT / NB, THREADS, 0, stream>>>(h, enc, Mt2, W2t, out);
}